// Round 6
// baseline (252.402 us; speedup 1.0000x reference)
//
#include <hip/hip_runtime.h>
#include <math.h>

#define G 8
#define Hd 256
#define Wd 256
#define HW (Hd * Wd)

typedef float fvec4 __attribute__((ext_vector_type(4)));

// ---------------------------------------------------------------------------
// v7 = v5 (position-packed GLCM, 512x1024, verified 93 us) + three latency
// fixes, none touching the verified GLCM math:
//   1. depth-2 row prefetch (vn1, vn2): 2 outstanding 1KB loads/wave doubles
//      in-flight bytes; GLCM phase was read-BW-limited at 3.7 TB/s (v5 cut
//      VALU 15% with zero wall change -> non-VALU floor = HBM read).
//   2. early scale loads (k=0..7) issued AFTER the hist-atomics barrier --
//      the epilogue region where most waves idle; latency completes under
//      the feature/MLP phase. (v6 placed them BEFORE the barrier: the
//      vmcnt(0)-before-s_barrier drain stalled the critical path. Reverted.)
//   3. second scale half batched 8-deep (was ~2 loads in flight at VGPR=32).
// Register discipline: e-regs live only after GLCM state dies; peak must
// stay <= 64 VGPR (32-waves/CU cliff).
//
// GLCM core (verified v4/v5):
//   lane L covers columns 4L..4L+3 via ONE global_load_dwordx4 per row;
//   bit b of position-k mask <-> column 4b+k; shifted j-masks are register
//   renames for 3 of 4 positions (only mjl_0/mjr_3 are real shifts).
//   Lane L owns bin L (i = L>>3, j = L&7); Mi is a lane permutation of MJ
//   (mi[L] = MJ[L>>3], ds_bpermute pair) consumed one row later; cnt0
//   (angle 0, same-row left neighbor) deferred one row through MJp/mjl0p.
// Pair semantics (d=1, angles 0, pi/4, pi/2, 3pi/4), zero-padded borders;
// OOB neighbor -> q=0 -> bin j=0 (JL0/JR0 pad bits, MJPAD pad row).
// ---------------------------------------------------------------------------
__global__ __launch_bounds__(1024) void glcm_fused(const float* __restrict__ x,
                                                   const float* __restrict__ W1,
                                                   const float* __restrict__ W2,
                                                   float* __restrict__ out) {
    __shared__ unsigned int hist[4 * 64];   // [angle][i*8+j]
    __shared__ float feats_s[16];
    __shared__ float h_s[16];
    __shared__ float wplus_s;

    const int t = threadIdx.x;
    const int bc = blockIdx.x;              // b*64 + c
    const float* img = x + (size_t)bc * HW;
    const fvec4* img4 = (const fvec4*)img;  // row y = img4[y*64 + lane]

    if (t < 256) hist[t] = 0u;

    const int lane = t & 63;
    const int wv = t >> 6;                  // 0..15
    const int r0 = wv << 4;                 // first owned row

    // j-selectors (j = lane&7): XNOR-select composition of ballot bitplanes.
    const unsigned long long F0 = (lane & 1) ? 0ull : ~0ull;
    const unsigned long long F1 = (lane & 2) ? 0ull : ~0ull;
    const unsigned long long F2 = (lane & 4) ? 0ull : ~0ull;
    const unsigned long long MJPAD = F0 & F1 & F2;        // mask of a zero-pad row
    const unsigned long long JL0 = MJPAD & 1ull;          // left-edge pad bit
    const unsigned long long JR0 = MJPAD & (1ull << 63);  // right-edge pad bit
    const int baddr = (lane >> 3) << 2;     // ds_bpermute byte addr: lane i(L)

    unsigned int cnt0 = 0, cnt1 = 0, cnt2 = 0, cnt3 = 0;

    unsigned long long MJ[4];               // j-match masks, current row, per pos
    unsigned long long Mi_prev[4];          // i-match masks of previous row
    unsigned long long MJp[3];              // prev row MJ[0..2] (for deferred cnt0)
    unsigned long long mjl0p;               // prev row mjl_0

    auto bperm64 = [&](unsigned long long v) -> unsigned long long {
        const unsigned int lo =
            (unsigned int)__builtin_amdgcn_ds_bpermute(baddr, (int)(unsigned int)v);
        const unsigned int hi =
            (unsigned int)__builtin_amdgcn_ds_bpermute(baddr, (int)(unsigned int)(v >> 32));
        return ((unsigned long long)hi << 32) | lo;
    };
    auto make_mj = [&](fvec4 v) {
        #pragma unroll
        for (int k = 0; k < 4; ++k) {
            const float r = v[k] * 7.0f;
            const int q = (int)r;
            const unsigned long long b0 = __ballot(q & 1);
            const unsigned long long b1 = __ballot(q & 2);
            const unsigned long long b2 = __ballot(r >= 4.0f);
            MJ[k] = (b0 ^ F0) & (b1 ^ F1) & (b2 ^ F2);
        }
    };

    // ---- prologue: rows r0 (compute), r0+1, r0+2 prefetched (depth 2).
    //      r0 <= 240 so r0+2 <= 242 < Hd always. ----
    fvec4 vn1, vn2;
    {
        const fvec4 vc0 = img4[r0 * 64 + lane];
        vn1 = img4[(r0 + 1) * 64 + lane];
        vn2 = img4[(r0 + 2) * 64 + lane];
        make_mj(vc0);
        MJp[0] = MJ[0]; MJp[1] = MJ[1]; MJp[2] = MJ[2];
        mjl0p = (MJ[3] << 1) | JL0;
        #pragma unroll
        for (int k = 0; k < 4; ++k) Mi_prev[k] = bperm64(MJ[k]);
    }

    // ---- rows r0+1 .. r0+15 (dynamic loop; depth-2 SW pipeline) ----
    for (int yy = 1; yy < 16; ++yy) {
        const fvec4 cur = vn1;              // row r0+yy
        vn1 = vn2;
        if (yy < 15) {                      // wave-uniform guards
            const int yn = r0 + yy + 2;     // future row; only r0+16 can be OOB
            if (yn < Hd) vn2 = img4[yn * 64 + lane];
        }
        make_mj(cur);
        const unsigned long long mjl0 = (MJ[3] << 1) | JL0;
        const unsigned long long mjr3 = (MJ[0] >> 1) | JR0;

        // angle0 of row yy-1 (deferred): same-row left neighbor
        cnt0 += __popcll(Mi_prev[0] & mjl0p) + __popcll(Mi_prev[1] & MJp[0])
              + __popcll(Mi_prev[2] & MJp[1]) + __popcll(Mi_prev[3] & MJp[2]);
        // angle1: down-left     angle2: down      angle3: down-right
        cnt1 += __popcll(Mi_prev[0] & mjl0)  + __popcll(Mi_prev[1] & MJ[0])
              + __popcll(Mi_prev[2] & MJ[1]) + __popcll(Mi_prev[3] & MJ[2]);
        cnt2 += __popcll(Mi_prev[0] & MJ[0]) + __popcll(Mi_prev[1] & MJ[1])
              + __popcll(Mi_prev[2] & MJ[2]) + __popcll(Mi_prev[3] & MJ[3]);
        cnt3 += __popcll(Mi_prev[0] & MJ[1]) + __popcll(Mi_prev[1] & MJ[2])
              + __popcll(Mi_prev[2] & MJ[3]) + __popcll(Mi_prev[3] & mjr3);

        MJp[0] = MJ[0]; MJp[1] = MJ[1]; MJp[2] = MJ[2];
        mjl0p = mjl0;
        #pragma unroll
        for (int k = 0; k < 4; ++k) Mi_prev[k] = bperm64(MJ[k]);
    }

    // ---- boundary row r0+16 (next wave's first row, held in vn1; or pad) ----
    if (r0 + 16 < Hd) {
        make_mj(vn1);
    } else {
        #pragma unroll
        for (int k = 0; k < 4; ++k) MJ[k] = MJPAD;
    }
    {
        const unsigned long long mjl0 = (MJ[3] << 1) | JL0;
        const unsigned long long mjr3 = (MJ[0] >> 1) | JR0;
        cnt0 += __popcll(Mi_prev[0] & mjl0p) + __popcll(Mi_prev[1] & MJp[0])
              + __popcll(Mi_prev[2] & MJp[1]) + __popcll(Mi_prev[3] & MJp[2]);
        cnt1 += __popcll(Mi_prev[0] & mjl0)  + __popcll(Mi_prev[1] & MJ[0])
              + __popcll(Mi_prev[2] & MJ[1]) + __popcll(Mi_prev[3] & MJ[2]);
        cnt2 += __popcll(Mi_prev[0] & MJ[0]) + __popcll(Mi_prev[1] & MJ[1])
              + __popcll(Mi_prev[2] & MJ[2]) + __popcll(Mi_prev[3] & MJ[3]);
        cnt3 += __popcll(Mi_prev[0] & MJ[1]) + __popcll(Mi_prev[1] & MJ[2])
              + __popcll(Mi_prev[2] & MJ[3]) + __popcll(Mi_prev[3] & mjr3);
    }

    __syncthreads();                        // hist init visible
    atomicAdd(&hist[  0 + lane], cnt0);
    atomicAdd(&hist[ 64 + lane], cnt1);
    atomicAdd(&hist[128 + lane], cnt2);
    atomicAdd(&hist[192 + lane], cnt3);
    __syncthreads();                        // hist complete

    // ---- early scale loads (k=0..7), AFTER the hist barrier: issued into
    //      the epilogue region where most waves idle; L3-resident lines;
    //      latency completes under the feature/MLP phase. GLCM registers
    //      are dead here, so these 32 VGPRs don't raise the peak past 64. ----
    fvec4 e0 = img4[0 * 1024 + t];
    fvec4 e1 = img4[1 * 1024 + t];
    fvec4 e2 = img4[2 * 1024 + t];
    fvec4 e3 = img4[3 * 1024 + t];
    fvec4 e4 = img4[4 * 1024 + t];
    fvec4 e5 = img4[5 * 1024 + t];
    fvec4 e6 = img4[6 * 1024 + t];
    fvec4 e7 = img4[7 * 1024 + t];

    // ---- features: wave a (t<256) handles angle a; 64 bins = 64 lanes ----
    if (t < 256) {
        float csum, hsum, esum, rsum;
        {
            const int a = t >> 6;
            const int bin = t & 63;
            const float p = (float)hist[a * 64 + bin] * (1.0f / 65536.0f);
            const int i = bin >> 3, j = bin & 7;
            const int dij = i - j;
            const int adij = dij < 0 ? -dij : dij;
            csum = (float)(dij * dij) * p;
            hsum = p / (float)(1 + adij);
            esum = p * p;
            rsum = ((float)i - 3.5f) * ((float)j - 3.5f) * p;
        }
        #pragma unroll
        for (int m = 1; m < 64; m <<= 1) {
            csum += __shfl_xor(csum, m, 64);
            hsum += __shfl_xor(hsum, m, 64);
            esum += __shfl_xor(esum, m, 64);
            rsum += __shfl_xor(rsum, m, 64);
        }
        if ((t & 63) == 0) {
            const int a = t >> 6;
            feats_s[a * 4 + 0] = csum;
            feats_s[a * 4 + 1] = hsum;
            feats_s[a * 4 + 2] = esum;
            // I_STD^2 + 1e-6, I_STD = sqrt(6) (ddof=1 std of arange(8))
            feats_s[a * 4 + 3] = rsum * (1.0f / 6.000001f);
        }
    }
    __syncthreads();

    // ---- MLP: h = relu(feats @ W1); z = h @ W2[:, c]; w = sigmoid(z) ----
    if (t < 16) {
        float acc = 0.0f;
        #pragma unroll
        for (int f = 0; f < 16; ++f) acc += feats_s[f] * W1[f * 16 + t];
        h_s[t] = acc > 0.0f ? acc : 0.0f;
    }
    __syncthreads();
    if (t == 0) {
        const int c = bc & 63;
        float z = 0.0f;
        #pragma unroll
        for (int k = 0; k < 16; ++k) z += h_s[k] * W2[k * 64 + c];
        const float w = 1.0f / (1.0f + expf(-z));
        wplus_s = w + 1.0f;
    }
    __syncthreads();

    // ---- fused scale: held half is mul+store only; second half 8-deep ----
    const float w = wplus_s;
    fvec4* out4 = (fvec4*)(out + (size_t)bc * HW);

    e0 *= w; e1 *= w; e2 *= w; e3 *= w;
    e4 *= w; e5 *= w; e6 *= w; e7 *= w;
    __builtin_nontemporal_store(e0, &out4[0 * 1024 + t]);
    __builtin_nontemporal_store(e1, &out4[1 * 1024 + t]);
    __builtin_nontemporal_store(e2, &out4[2 * 1024 + t]);
    __builtin_nontemporal_store(e3, &out4[3 * 1024 + t]);
    __builtin_nontemporal_store(e4, &out4[4 * 1024 + t]);
    __builtin_nontemporal_store(e5, &out4[5 * 1024 + t]);
    __builtin_nontemporal_store(e6, &out4[6 * 1024 + t]);
    __builtin_nontemporal_store(e7, &out4[7 * 1024 + t]);

    {   // k = 8..15: 8 loads in flight, then 8 mul+NT stores
        fvec4 a = img4[ 8 * 1024 + t];
        fvec4 b = img4[ 9 * 1024 + t];
        fvec4 c = img4[10 * 1024 + t];
        fvec4 d = img4[11 * 1024 + t];
        fvec4 e = img4[12 * 1024 + t];
        fvec4 f = img4[13 * 1024 + t];
        fvec4 g = img4[14 * 1024 + t];
        fvec4 h = img4[15 * 1024 + t];
        a *= w; b *= w; c *= w; d *= w; e *= w; f *= w; g *= w; h *= w;
        __builtin_nontemporal_store(a, &out4[ 8 * 1024 + t]);
        __builtin_nontemporal_store(b, &out4[ 9 * 1024 + t]);
        __builtin_nontemporal_store(c, &out4[10 * 1024 + t]);
        __builtin_nontemporal_store(d, &out4[11 * 1024 + t]);
        __builtin_nontemporal_store(e, &out4[12 * 1024 + t]);
        __builtin_nontemporal_store(f, &out4[13 * 1024 + t]);
        __builtin_nontemporal_store(g, &out4[14 * 1024 + t]);
        __builtin_nontemporal_store(h, &out4[15 * 1024 + t]);
    }
}

extern "C" void kernel_launch(void* const* d_in, const int* in_sizes, int n_in,
                              void* d_out, int out_size, void* d_ws, size_t ws_size,
                              hipStream_t stream) {
    (void)in_sizes; (void)n_in; (void)d_ws; (void)ws_size; (void)out_size;
    const float* x  = (const float*)d_in[0];
    const float* W1 = (const float*)d_in[1];   // (16,16) row-major
    const float* W2 = (const float*)d_in[2];   // (16,64) row-major
    float* out = (float*)d_out;

    glcm_fused<<<512, 1024, 0, stream>>>(x, W1, W2, out);
}